// Round 5
// baseline (45.914 us; speedup 1.0000x reference)
//
#include <hip/hip_runtime.h>

// FastGuidedFilter, fully fused, 8 highres rows per block.
// Per block (channel, 8 hr rows):
//  0. issue ALL 8 highres-row float4 loads first (HBM latency hides under 1-4)
//  1. stage 8 lowres rows of x,y in LDS (zero outside image -> all windows static)
//  2. per-thread column: 16 stride-1 LDS reads -> 4 vertical window sums in regs
//     -> one float4 {sx,sy,sxy,sxx} col-sum per A/b row into zero-padded LDS
//  3. horizontal: 5 ds_read_b128 taps per row -> stats -> A,b (4 rows) in LDS
//  4. x-interp A,b per hr column into registers (static indices only)
//  5. per hr row: 4-weight y-interp + out = A*x_hr + b, nontemporal store
// LDS: stage region (16 KB) aliased with col-sum region (16.6 KB) + A/B (8 KB)
//      = 24.8 KB -> 6 blocks/CU. 4 barriers per 8 hr rows.

typedef float f4 __attribute__((ext_vector_type(4)));

constexpr int H_LR = 256, W_LR = 256;
constexpr int H_HR = 1024, W_HR = 1024;
constexpr int NC   = 24;       // 8 * 3
constexpr int RAD  = 2;        // kernel_size 5
constexpr int RPB  = 8;        // highres rows per block

constexpr int CS_W    = W_LR + 4;            // 260: zero-padded col-sum width
constexpr int CS_BYTES = 4 * CS_W * 4 * 4;   // 16640
constexpr int AB_OFF  = CS_BYTES;            // 16-aligned (1040*16)

__global__ void __launch_bounds__(256) fgf_fused(const float* __restrict__ xlr,
                                                 const float* __restrict__ ylr,
                                                 const float* __restrict__ xhr,
                                                 float* __restrict__ out) {
    __shared__ __align__(16) char lds[CS_BYTES + 2 * 4 * W_LR * 4];  // 24832 B
    auto sx = reinterpret_cast<float(*)[W_LR]>(lds);                 // [8][256]
    auto sy = reinterpret_cast<float(*)[W_LR]>(lds + 8 * W_LR * 4);  // [8][256]
    auto cs = reinterpret_cast<float(*)[CS_W][4]>(lds);              // [4][260][4]
    auto ab = reinterpret_cast<float(*)[W_LR][2]>(lds + AB_OFF);     // [4][256][2]

    const int c  = blockIdx.y;
    const int i0 = blockIdx.x * RPB;
    const int t  = (int)threadIdx.x;
    const float scale = (float)(H_LR - 1) / (float)(H_HR - 1);       // 255/1023

    const int y0min = (int)((float)i0 * scale);                      // floor, >= 0

    // ---- 0. issue all 8 highres-row loads up front (latency hides under 1-4)
    const size_t hrbase = ((size_t)c << 20) + (size_t)i0 * W_HR + t * 4;
    f4 xv[RPB];
    #pragma unroll
    for (int k = 0; k < RPB; ++k)
        xv[k] = *(const f4*)(xhr + hrbase + (size_t)k * W_HR);

    // ---- 1. stage lowres rows y0min-2 .. y0min+5 (zero outside image)
    const int lrbase = c * (H_LR * W_LR);
    #pragma unroll
    for (int half = 0; half < 2; ++half) {
        const int idx = half * 256 + t;            // 0..511
        const int lr = idx >> 6, q = idx & 63;
        const int gr = y0min - 2 + lr;
        f4 vx = {0.f, 0.f, 0.f, 0.f};
        f4 vy = {0.f, 0.f, 0.f, 0.f};
        if (gr >= 0 && gr < H_LR) {
            vx = *(const f4*)(xlr + lrbase + gr * W_LR + q * 4);
            vy = *(const f4*)(ylr + lrbase + gr * W_LR + q * 4);
        }
        *(f4*)&sx[lr][q * 4] = vx;
        *(f4*)&sy[lr][q * 4] = vy;
    }
    __syncthreads();

    // ---- 2. vertical window sums (registers), column t
    float vx[8], vy[8];
    #pragma unroll
    for (int l = 0; l < 8; ++l) { vx[l] = sx[l][t]; vy[l] = sy[l][t]; }
    __syncthreads();                               // staging reads done; cs may alias

    #pragma unroll
    for (int rr = 0; rr < 4; ++rr) {               // A/b row y0min+rr (may be >255: unused)
        float a = 0.f, b = 0.f, cxy = 0.f, cxx = 0.f;
        #pragma unroll
        for (int l = rr; l < rr + 5; ++l) {        // static after unroll
            a += vx[l]; b += vy[l]; cxy += vx[l] * vy[l]; cxx += vx[l] * vx[l];
        }
        f4 v = {a, b, cxy, cxx};
        *(f4*)&cs[rr][t + 2][0] = v;
    }
    if (t < 2) {                                   // zero-pad columns
        const f4 z = {0.f, 0.f, 0.f, 0.f};
        #pragma unroll
        for (int rr = 0; rr < 4; ++rr) {
            *(f4*)&cs[rr][t][0] = z;
            *(f4*)&cs[rr][t + W_LR + 2][0] = z;
        }
    }
    __syncthreads();

    // ---- 3. horizontal 5-tap + stats -> A,b
    const int hcnt = min(t + RAD, W_LR - 1) - max(t - RAD, 0) + 1;
    #pragma unroll
    for (int rr = 0; rr < 4; ++rr) {
        f4 s = {0.f, 0.f, 0.f, 0.f};
        #pragma unroll
        for (int d = 0; d < 5; ++d) s += *(const f4*)&cs[rr][t + d][0];
        const int r  = y0min + rr;                 // may exceed 255; vcnt stays >=1
        const int v0 = max(r - RAD, 0), v1 = min(r + RAD, H_LR - 1);
        const float inv = 1.0f / (float)((v1 - v0 + 1) * hcnt);
        const float mx  = s.x * inv;
        const float my  = s.y * inv;
        const float cov = s.z * inv - mx * my;
        const float var = s.w * inv - mx * mx;
        const float a   = cov / (var + 1e-8f);
        ab[rr][t][0] = a;
        ab[rr][t][1] = my - a * mx;
    }
    __syncthreads();

    // ---- 4. x-interp per hr column (4 cols/thread), all 4 A/b rows
    float ax[4][4], bx[4][4];                      // [rr][m], static indices only
    #pragma unroll
    for (int m = 0; m < 4; ++m) {
        const int   j   = t * 4 + m;
        const float fx  = (float)j * scale;
        const int   x0  = (int)fx;
        const float wx  = fx - (float)x0;
        const int   x1  = min(x0 + 1, W_LR - 1);
        const float wx0 = 1.f - wx;
        #pragma unroll
        for (int rr = 0; rr < 4; ++rr) {
            ax[rr][m] = ab[rr][x0][0] * wx0 + ab[rr][x1][0] * wx;
            bx[rr][m] = ab[rr][x0][1] * wx0 + ab[rr][x1][1] * wx;
        }
    }

    // ---- 5. per hr row: 4-weight y-interp + apply
    #pragma unroll
    for (int k = 0; k < RPB; ++k) {
        const int   i   = i0 + k;
        const float fy  = (float)i * scale;
        const int   yy0 = (int)fy;
        const float wy  = fy - (float)yy0;
        const int   l0  = yy0 - y0min;                       // 0..2
        const int   l1  = min(yy0 + 1, H_LR - 1) - y0min;    // 0..3
        const float w0  = (l0 == 0 ? 1.f - wy : 0.f) + (l1 == 0 ? wy : 0.f);
        const float w1  = (l0 == 1 ? 1.f - wy : 0.f) + (l1 == 1 ? wy : 0.f);
        const float w2  = (l0 == 2 ? 1.f - wy : 0.f) + (l1 == 2 ? wy : 0.f);
        const float w3  = (l1 == 3 ? wy : 0.f);

        f4 ov;
        #pragma unroll
        for (int m = 0; m < 4; ++m) {
            const float a = ax[0][m] * w0 + ax[1][m] * w1 + ax[2][m] * w2 + ax[3][m] * w3;
            const float b = bx[0][m] * w0 + bx[1][m] * w1 + bx[2][m] * w2 + bx[3][m] * w3;
            ov[m] = a * xv[k][m] + b;
        }
        __builtin_nontemporal_store(ov, (f4*)(out + hrbase + (size_t)k * W_HR));
    }
}

extern "C" void kernel_launch(void* const* d_in, const int* in_sizes, int n_in,
                              void* d_out, int out_size, void* d_ws, size_t ws_size,
                              hipStream_t stream) {
    const float* x_lr = (const float*)d_in[0];  // input_lowres  [8,3,256,256]
    const float* y_lr = (const float*)d_in[1];  // guide_lowres  [8,3,256,256]
    const float* x_hr = (const float*)d_in[2];  // input_highres [8,3,1024,1024]
    float* out = (float*)d_out;

    dim3 grid(H_HR / RPB, NC, 1);               // 128 x 24 = 3072 blocks
    fgf_fused<<<grid, 256, 0, stream>>>(x_lr, y_lr, x_hr, out);
}

// Round 6
// 41.925 us; speedup vs baseline: 1.0951x; 1.0951x over previous
//
#include <hip/hip_runtime.h>

// FastGuidedFilter, fully fused, 8 highres rows per block.
// Per block (channel, 8 hr rows):
//  1a. issue lowres staging loads (4 f4), THEN the 8 highres-row f4 loads
//      (staging is older in the vmcnt FIFO -> ds_writes wait only on staging;
//       xv HBM latency hides under the whole LDS pipeline)
//  1b. ds_write staged rows (zero outside image -> all windows static)
//  2. per-thread column: 16 stride-1 LDS reads -> 4 vertical window sums
//     -> one float4 {sx,sy,sxy,sxx} col-sum per A/b row into zero-padded LDS
//  3. horizontal: 5 ds_read_b128 taps per row -> stats -> regs
//  4. A,b to LDS (aliases dead col-sum region), x-interp into registers
//  5. per hr row: 4-weight y-interp + out = A*x_hr + b, nontemporal store
// LDS: ONE 16.6 KB region aliased across {staging 16.4K, col-sums 16.6K, ab 8K}
//      -> 8 blocks/CU (wave-capped). 5 barriers per 8 hr rows.

typedef float f4 __attribute__((ext_vector_type(4)));

constexpr int H_LR = 256, W_LR = 256;
constexpr int H_HR = 1024, W_HR = 1024;
constexpr int NC   = 24;       // 8 * 3
constexpr int RAD  = 2;        // kernel_size 5
constexpr int RPB  = 8;        // highres rows per block

constexpr int CS_W      = W_LR + 4;              // 260: zero-padded col-sum width
constexpr int LDS_BYTES = 4 * CS_W * 4 * 4;      // 16640 B total

__global__ void __launch_bounds__(256) fgf_fused(const float* __restrict__ xlr,
                                                 const float* __restrict__ ylr,
                                                 const float* __restrict__ xhr,
                                                 float* __restrict__ out) {
    __shared__ __align__(16) char lds[LDS_BYTES];
    auto sx = reinterpret_cast<float(*)[W_LR]>(lds);                  // [8][256]
    auto sy = reinterpret_cast<float(*)[W_LR]>(lds + 8 * W_LR * 4);   // [8][256]
    auto cs = reinterpret_cast<float(*)[CS_W][4]>(lds);               // [4][260][4]
    auto ab = reinterpret_cast<float(*)[W_LR][2]>(lds);               // [4][256][2]

    const int c  = blockIdx.y;
    const int i0 = blockIdx.x * RPB;
    const int t  = (int)threadIdx.x;
    const float scale = (float)(H_LR - 1) / (float)(H_HR - 1);        // 255/1023

    const int y0min = (int)((float)i0 * scale);                       // floor, >= 0

    // ---- 1a. staging loads FIRST (oldest in vmcnt FIFO), then xv loads
    const int lrbase = c * (H_LR * W_LR);
    f4 stx[2], sty[2];
    int lr_[2], q_[2];
    #pragma unroll
    for (int half = 0; half < 2; ++half) {
        const int idx = half * 256 + t;            // 0..511
        lr_[half] = idx >> 6;                      // local row 0..7
        q_[half]  = idx & 63;                      // float4 column
        const int gr = y0min - 2 + lr_[half];
        f4 vx = {0.f, 0.f, 0.f, 0.f};
        f4 vy = {0.f, 0.f, 0.f, 0.f};
        if (gr >= 0 && gr < H_LR) {
            vx = *(const f4*)(xlr + lrbase + gr * W_LR + q_[half] * 4);
            vy = *(const f4*)(ylr + lrbase + gr * W_LR + q_[half] * 4);
        }
        stx[half] = vx;
        sty[half] = vy;
    }
    const size_t hrbase = ((size_t)c << 20) + (size_t)i0 * W_HR + t * 4;
    f4 xv[RPB];
    #pragma unroll
    for (int k = 0; k < RPB; ++k)
        xv[k] = *(const f4*)(xhr + hrbase + (size_t)k * W_HR);

    // ---- 1b. write staged rows
    #pragma unroll
    for (int half = 0; half < 2; ++half) {
        *(f4*)&sx[lr_[half]][q_[half] * 4] = stx[half];
        *(f4*)&sy[lr_[half]][q_[half] * 4] = sty[half];
    }
    __syncthreads();                               // (1)

    // ---- 2. vertical window sums (registers), column t
    float vx[8], vy[8];
    #pragma unroll
    for (int l = 0; l < 8; ++l) { vx[l] = sx[l][t]; vy[l] = sy[l][t]; }
    __syncthreads();                               // (2) staging reads done; cs aliases

    #pragma unroll
    for (int rr = 0; rr < 4; ++rr) {               // A/b row y0min+rr (>255 -> unused)
        float a = 0.f, b = 0.f, cxy = 0.f, cxx = 0.f;
        #pragma unroll
        for (int l = rr; l < rr + 5; ++l) {        // static after unroll
            a += vx[l]; b += vy[l]; cxy += vx[l] * vy[l]; cxx += vx[l] * vx[l];
        }
        f4 v = {a, b, cxy, cxx};
        *(f4*)&cs[rr][t + 2][0] = v;
    }
    if (t < 2) {                                   // zero-pad columns
        const f4 z = {0.f, 0.f, 0.f, 0.f};
        #pragma unroll
        for (int rr = 0; rr < 4; ++rr) {
            *(f4*)&cs[rr][t][0] = z;
            *(f4*)&cs[rr][t + W_LR + 2][0] = z;
        }
    }
    __syncthreads();                               // (3)

    // ---- 3. horizontal 5-tap + stats -> registers
    const int hcnt = min(t + RAD, W_LR - 1) - max(t - RAD, 0) + 1;
    float aa[4], bb[4];
    #pragma unroll
    for (int rr = 0; rr < 4; ++rr) {
        f4 s = {0.f, 0.f, 0.f, 0.f};
        #pragma unroll
        for (int d = 0; d < 5; ++d) s += *(const f4*)&cs[rr][t + d][0];
        const int r  = y0min + rr;                 // may exceed 255; vcnt stays >=1
        const int v0 = max(r - RAD, 0), v1 = min(r + RAD, H_LR - 1);
        const float inv = 1.0f / (float)((v1 - v0 + 1) * hcnt);
        const float mx  = s.x * inv;
        const float my  = s.y * inv;
        const float cov = s.z * inv - mx * my;
        const float var = s.w * inv - mx * mx;
        aa[rr] = cov / (var + 1e-8f);
        bb[rr] = my - aa[rr] * mx;
    }
    __syncthreads();                               // (4) cs reads done; ab aliases

    #pragma unroll
    for (int rr = 0; rr < 4; ++rr) {
        ab[rr][t][0] = aa[rr];
        ab[rr][t][1] = bb[rr];
    }
    __syncthreads();                               // (5)

    // ---- 4. x-interp per hr column (4 cols/thread), all 4 A/b rows
    float ax[4][4], bx[4][4];                      // [rr][m], static indices only
    #pragma unroll
    for (int m = 0; m < 4; ++m) {
        const int   j   = t * 4 + m;
        const float fx  = (float)j * scale;
        const int   x0  = (int)fx;
        const float wx  = fx - (float)x0;
        const int   x1  = min(x0 + 1, W_LR - 1);
        const float wx0 = 1.f - wx;
        #pragma unroll
        for (int rr = 0; rr < 4; ++rr) {
            ax[rr][m] = ab[rr][x0][0] * wx0 + ab[rr][x1][0] * wx;
            bx[rr][m] = ab[rr][x0][1] * wx0 + ab[rr][x1][1] * wx;
        }
    }

    // ---- 5. per hr row: 4-weight y-interp + apply
    #pragma unroll
    for (int k = 0; k < RPB; ++k) {
        const int   i   = i0 + k;
        const float fy  = (float)i * scale;
        const int   yy0 = (int)fy;
        const float wy  = fy - (float)yy0;
        const int   l0  = yy0 - y0min;                       // 0..2
        const int   l1  = min(yy0 + 1, H_LR - 1) - y0min;    // 0..3
        const float w0  = (l0 == 0 ? 1.f - wy : 0.f) + (l1 == 0 ? wy : 0.f);
        const float w1  = (l0 == 1 ? 1.f - wy : 0.f) + (l1 == 1 ? wy : 0.f);
        const float w2  = (l0 == 2 ? 1.f - wy : 0.f) + (l1 == 2 ? wy : 0.f);
        const float w3  = (l1 == 3 ? wy : 0.f);

        f4 ov;
        #pragma unroll
        for (int m = 0; m < 4; ++m) {
            const float a = ax[0][m] * w0 + ax[1][m] * w1 + ax[2][m] * w2 + ax[3][m] * w3;
            const float b = bx[0][m] * w0 + bx[1][m] * w1 + bx[2][m] * w2 + bx[3][m] * w3;
            ov[m] = a * xv[k][m] + b;
        }
        __builtin_nontemporal_store(ov, (f4*)(out + hrbase + (size_t)k * W_HR));
    }
}

extern "C" void kernel_launch(void* const* d_in, const int* in_sizes, int n_in,
                              void* d_out, int out_size, void* d_ws, size_t ws_size,
                              hipStream_t stream) {
    const float* x_lr = (const float*)d_in[0];  // input_lowres  [8,3,256,256]
    const float* y_lr = (const float*)d_in[1];  // guide_lowres  [8,3,256,256]
    const float* x_hr = (const float*)d_in[2];  // input_highres [8,3,1024,1024]
    float* out = (float*)d_out;

    dim3 grid(H_HR / RPB, NC, 1);               // 128 x 24 = 3072 blocks
    fgf_fused<<<grid, 256, 0, stream>>>(x_lr, y_lr, x_hr, out);
}